// Round 1
// baseline (185.785 us; speedup 1.0000x reference)
//
#include <hip/hip_runtime.h>
#include <hip/hip_bf16.h>

typedef __attribute__((ext_vector_type(8))) short bf16x8;
typedef __attribute__((ext_vector_type(8))) unsigned short u16x8;
typedef __attribute__((ext_vector_type(4))) unsigned short u16x4;
typedef __attribute__((ext_vector_type(4))) float f32x4;

__device__ __forceinline__ unsigned short f2bf(float f) {
    __hip_bfloat16 h = __float2bfloat16(f);
    return *reinterpret_cast<unsigned short*>(&h);
}

// ---------------------------------------------------------------------------
// Kernel 1: pack W^T bf16: wt[(sel*128+n)*2048 + k] = w_sel[k*128 + n]
// ---------------------------------------------------------------------------
__global__ __launch_bounds__(256) void pack_w(
    const float* __restrict__ wq, const float* __restrict__ wk,
    const float* __restrict__ wv, unsigned short* __restrict__ wt)
{
    int idx = blockIdx.x * 256 + threadIdx.x;   // 786432 total
    int n   = idx & 127;
    int k   = (idx >> 7) & 2047;
    int sel = idx >> 18;                        // 0,1,2
    const float* w = (sel == 0) ? wq : (sel == 1) ? wk : wv;
    wt[(size_t)(sel * 128 + n) * 2048 + k] = f2bf(w[k * 128 + n]);
}

// ---------------------------------------------------------------------------
// Kernel 2: QKV GEMM (x fp32 -> bf16 staged) + RoPE epilogue.
//   tile 128x128, K-step 32, 4 waves (2x2), double LDS buffer, 1 barrier/step
//   ntile 0 -> Q (RoPE), 1 -> K (RoPE), 2 -> V stored transposed (128 x T)
// ---------------------------------------------------------------------------
__global__ __launch_bounds__(256) void qkv_gemm(
    const float* __restrict__ x, const unsigned short* __restrict__ wt,
    const float* __restrict__ rc, const float* __restrict__ rs,
    unsigned short* __restrict__ Qb, unsigned short* __restrict__ Kb,
    unsigned short* __restrict__ VT)
{
    __shared__ __align__(16) unsigned short As[2][128 * 32];
    __shared__ __align__(16) unsigned short Bs[2][128 * 32];

    const int bid   = blockIdx.x;           // 384
    const int slot  = bid & 7;              // XCD slot (round-robin assumption)
    const int idx   = bid >> 3;             // 0..47
    const int mtile = slot + 8 * (idx / 3); // 0..127 ; trio of ntiles shares XCD
    const int ntile = idx % 3;

    const int tid  = threadIdx.x;
    const int lane = tid & 63;
    const int wid  = tid >> 6;
    const int wm   = wid >> 1, wn = wid & 1;
    const int grp  = lane >> 4, cl = lane & 15;

    const int arow0 = tid >> 2;          // 0..63
    const int ak8   = tid & 3;           // which 8-float chunk of the 32-k row

    const float*          xbase = x  + (size_t)(mtile * 128) * 2048;
    const unsigned short* wbase = wt + (size_t)(ntile * 128) * 2048;

    float4 afl[2][2];
    u16x8  bwl[2];

    auto gload = [&](int ks) {
        int k0 = ks * 32 + ak8 * 8;
        #pragma unroll
        for (int i = 0; i < 2; ++i) {
            int row = arow0 + i * 64;
            const float* p = xbase + (size_t)row * 2048 + k0;
            afl[i][0] = *reinterpret_cast<const float4*>(p);
            afl[i][1] = *reinterpret_cast<const float4*>(p + 4);
            bwl[i]    = *reinterpret_cast<const u16x8*>(wbase + (size_t)row * 2048 + k0);
        }
    };
    auto swrite = [&](int buf) {
        #pragma unroll
        for (int i = 0; i < 2; ++i) {
            int row = arow0 + i * 64;
            u16x8 u;
            u[0] = f2bf(afl[i][0].x); u[1] = f2bf(afl[i][0].y);
            u[2] = f2bf(afl[i][0].z); u[3] = f2bf(afl[i][0].w);
            u[4] = f2bf(afl[i][1].x); u[5] = f2bf(afl[i][1].y);
            u[6] = f2bf(afl[i][1].z); u[7] = f2bf(afl[i][1].w);
            *reinterpret_cast<u16x8*>(&As[buf][row * 32 + ak8 * 8]) = u;
            *reinterpret_cast<u16x8*>(&Bs[buf][row * 32 + ak8 * 8]) = bwl[i];
        }
    };

    const f32x4 fz = {0.f, 0.f, 0.f, 0.f};
    f32x4 acc[4][4];
    #pragma unroll
    for (int mf = 0; mf < 4; ++mf)
        #pragma unroll
        for (int nf = 0; nf < 4; ++nf) acc[mf][nf] = fz;

    gload(0);
    swrite(0);
    __syncthreads();

    for (int ks = 0; ks < 64; ++ks) {
        int cur = ks & 1;
        if (ks < 63) gload(ks + 1);

        bf16x8 a[4], b[4];
        #pragma unroll
        for (int mf = 0; mf < 4; ++mf)
            a[mf] = *reinterpret_cast<const bf16x8*>(
                &As[cur][(wm * 64 + mf * 16 + cl) * 32 + grp * 8]);
        #pragma unroll
        for (int nf = 0; nf < 4; ++nf)
            b[nf] = *reinterpret_cast<const bf16x8*>(
                &Bs[cur][(wn * 64 + nf * 16 + cl) * 32 + grp * 8]);
        #pragma unroll
        for (int mf = 0; mf < 4; ++mf)
            #pragma unroll
            for (int nf = 0; nf < 4; ++nf)
                acc[mf][nf] = __builtin_amdgcn_mfma_f32_16x16x32_bf16(
                    a[mf], b[nf], acc[mf][nf], 0, 0, 0);

        if (ks < 63) swrite(cur ^ 1);
        __syncthreads();
    }

    // Epilogue. C-layout: col = lane&15, row = (lane>>4)*4 + r
    if (ntile < 2) {
        unsigned short* dst = (ntile == 0) ? Qb : Kb;
        #pragma unroll
        for (int mf = 0; mf < 4; ++mf) {
            int mrow = mtile * 128 + wm * 64 + mf * 16 + grp * 4;
            #pragma unroll
            for (int nf = 0; nf < 4; ++nf) {
                int h = wn * 64 + nf * 16 + cl;
                #pragma unroll
                for (int r = 0; r < 4; ++r) {
                    int   m   = mrow + r;
                    int   t   = m & 2047;
                    float val = acc[mf][nf][r];
                    float pr  = __shfl_xor(val, 1, 64);  // partner column h^1
                    float cs  = rc[t * 128 + h];
                    float sn  = rs[t * 128 + h];
                    // q'[2i] = q[2i]c - q[2i+1]s ; q'[2i+1] = q[2i+1]c + q[2i]s
                    float res = (h & 1) ? fmaf(val, cs, pr * sn)
                                        : fmaf(val, cs, -pr * sn);
                    dst[(size_t)m * 128 + h] = f2bf(res);
                }
            }
        }
    } else {
        // V stored transposed: VT[(b*128 + h)*2048 + t], 4 consecutive t packed
        #pragma unroll
        for (int mf = 0; mf < 4; ++mf) {
            int mrow = mtile * 128 + wm * 64 + mf * 16 + grp * 4;
            int bb   = mrow >> 11;
            int t0   = mrow & 2047;
            #pragma unroll
            for (int nf = 0; nf < 4; ++nf) {
                int h = wn * 64 + nf * 16 + cl;
                u16x4 pk;
                #pragma unroll
                for (int r = 0; r < 4; ++r) pk[r] = f2bf(acc[mf][nf][r]);
                *reinterpret_cast<u16x4*>(&VT[(size_t)(bb * 128 + h) * 2048 + t0]) = pk;
            }
        }
    }
}

// ---------------------------------------------------------------------------
// Kernel 3: causal flash attention.
//   1 wave/block, 16 Q rows per wave, KV tile = 32, online softmax in-register,
//   P staged via small LDS tile (stride 40 -> 16B aligned, low bank conflict).
//   batch = bid%8 pins each batch's K/V to one XCD's L2.
// ---------------------------------------------------------------------------
__global__ __launch_bounds__(64) void flash_attn(
    const unsigned short* __restrict__ Qb, const unsigned short* __restrict__ Kb,
    const unsigned short* __restrict__ VT, float* __restrict__ out)
{
    __shared__ __align__(16) unsigned short P[16 * 40];

    const int bid = blockIdx.x;       // 1024
    const int b   = bid & 7;
    const int qt  = bid >> 3;         // 0..127
    const int lane = threadIdx.x;
    const int grp = lane >> 4, cl = lane & 15;
    const int m0  = qt << 4;
    const float scale = 0.08838834764831845f;   // 1/sqrt(128)

    bf16x8 aq[4];
    {
        const unsigned short* qp = Qb + (size_t)(b * 2048 + m0 + cl) * 128 + grp * 8;
        #pragma unroll
        for (int kc = 0; kc < 4; ++kc)
            aq[kc] = *reinterpret_cast<const bf16x8*>(qp + kc * 32);
    }

    const f32x4 fz = {0.f, 0.f, 0.f, 0.f};
    f32x4 o[8];
    #pragma unroll
    for (int nf = 0; nf < 8; ++nf) o[nf] = fz;
    float mrun[4], lrun[4];
    #pragma unroll
    for (int r = 0; r < 4; ++r) { mrun[r] = -INFINITY; lrun[r] = 0.f; }

    for (int s0 = 0; s0 <= m0 + 15; s0 += 32) {
        f32x4 sf0 = fz, sf1 = fz;
        const unsigned short* kp = Kb + (size_t)(b * 2048 + s0 + cl) * 128 + grp * 8;
        #pragma unroll
        for (int kc = 0; kc < 4; ++kc)
            sf0 = __builtin_amdgcn_mfma_f32_16x16x32_bf16(
                aq[kc], *reinterpret_cast<const bf16x8*>(kp + kc * 32), sf0, 0, 0, 0);
        kp += 16 * 128;
        #pragma unroll
        for (int kc = 0; kc < 4; ++kc)
            sf1 = __builtin_amdgcn_mfma_f32_16x16x32_bf16(
                aq[kc], *reinterpret_cast<const bf16x8*>(kp + kc * 32), sf1, 0, 0, 0);

        const bool notfull = (s0 + 31 > m0);
        float sv0[4], sv1[4], mx[4];
        #pragma unroll
        for (int r = 0; r < 4; ++r) {
            int   t  = m0 + grp * 4 + r;
            float a0 = sf0[r] * scale;
            float a1 = sf1[r] * scale;
            if (notfull) {
                if (s0 + cl > t)      a0 = -INFINITY;
                if (s0 + 16 + cl > t) a1 = -INFINITY;
            }
            sv0[r] = a0; sv1[r] = a1; mx[r] = fmaxf(a0, a1);
        }
        #pragma unroll
        for (int d = 1; d < 16; d <<= 1)
            #pragma unroll
            for (int r = 0; r < 4; ++r)
                mx[r] = fmaxf(mx[r], __shfl_xor(mx[r], d, 64));

        float psum[4], alpha[4];
        #pragma unroll
        for (int r = 0; r < 4; ++r) {
            float mn = fmaxf(mrun[r], mx[r]);
            alpha[r] = __expf(mrun[r] - mn);
            float p0 = __expf(sv0[r] - mn);
            float p1 = __expf(sv1[r] - mn);
            mrun[r]  = mn;
            psum[r]  = p0 + p1;
            P[(grp * 4 + r) * 40 + cl]      = f2bf(p0);
            P[(grp * 4 + r) * 40 + 16 + cl] = f2bf(p1);
        }
        #pragma unroll
        for (int d = 1; d < 16; d <<= 1)
            #pragma unroll
            for (int r = 0; r < 4; ++r)
                psum[r] += __shfl_xor(psum[r], d, 64);
        #pragma unroll
        for (int r = 0; r < 4; ++r)
            lrun[r] = lrun[r] * alpha[r] + psum[r];
        #pragma unroll
        for (int nf = 0; nf < 8; ++nf)
            #pragma unroll
            for (int r = 0; r < 4; ++r) o[nf][r] *= alpha[r];

        __syncthreads();
        bf16x8 pa = *reinterpret_cast<const bf16x8*>(&P[cl * 40 + grp * 8]);
        const unsigned short* vp = VT + (size_t)(b * 128 + cl) * 2048 + s0 + grp * 8;
        #pragma unroll
        for (int nf = 0; nf < 8; ++nf)
            o[nf] = __builtin_amdgcn_mfma_f32_16x16x32_bf16(
                pa, *reinterpret_cast<const bf16x8*>(vp + nf * 16 * 2048), o[nf], 0, 0, 0);
        __syncthreads();
    }

    float inv[4];
    #pragma unroll
    for (int r = 0; r < 4; ++r) inv[r] = 1.0f / lrun[r];
    #pragma unroll
    for (int nf = 0; nf < 8; ++nf)
        #pragma unroll
        for (int r = 0; r < 4; ++r)
            out[(size_t)(b * 2048 + m0 + grp * 4 + r) * 128 + nf * 16 + cl] =
                o[nf][r] * inv[r];
}

// ---------------------------------------------------------------------------
extern "C" void kernel_launch(void* const* d_in, const int* in_sizes, int n_in,
                              void* d_out, int out_size, void* d_ws, size_t ws_size,
                              hipStream_t stream)
{
    const float* x  = (const float*)d_in[0];
    const float* wq = (const float*)d_in[1];
    const float* wk = (const float*)d_in[2];
    const float* wv = (const float*)d_in[3];
    const float* rc = (const float*)d_in[4];
    const float* rs = (const float*)d_in[5];
    float* out = (float*)d_out;

    char* ws = (char*)d_ws;
    unsigned short* wt = (unsigned short*)(ws);                  // 1.5 MB
    unsigned short* Qb = (unsigned short*)(ws + (2u  << 20));    // 4 MB
    unsigned short* Kb = (unsigned short*)(ws + (6u  << 20));    // 4 MB
    unsigned short* VT = (unsigned short*)(ws + (10u << 20));    // 4 MB

    pack_w   <<<3072, 256, 0, stream>>>(wq, wk, wv, wt);
    qkv_gemm <<<384,  256, 0, stream>>>(x, wt, rc, rs, Qb, Kb, VT);
    flash_attn<<<1024, 64, 0, stream>>>(Qb, Kb, VT, out);
}

// Round 2
// 104.988 us; speedup vs baseline: 1.7696x; 1.7696x over previous
//
#include <hip/hip_runtime.h>
#include <hip/hip_bf16.h>

typedef __attribute__((ext_vector_type(8))) short bf16x8;
typedef __attribute__((ext_vector_type(8))) unsigned short u16x8;
typedef __attribute__((ext_vector_type(4))) unsigned short u16x4;
typedef __attribute__((ext_vector_type(4))) float f32x4;

__device__ __forceinline__ unsigned short f2bf(float f) {
    __hip_bfloat16 h = __float2bfloat16(f);
    return *reinterpret_cast<unsigned short*>(&h);
}

__device__ __forceinline__ void cp16(void* lds, const void* g) {
    __builtin_amdgcn_global_load_lds(
        (const __attribute__((address_space(1))) unsigned int*)g,
        (__attribute__((address_space(3))) unsigned int*)lds, 16, 0, 0);
}

// ---------------------------------------------------------------------------
// Kernel 1: pack W^T bf16: wt[(sel*128+n)*2048 + k] = w_sel[k*128 + n]
// ---------------------------------------------------------------------------
__global__ __launch_bounds__(256) void pack_w(
    const float* __restrict__ wq, const float* __restrict__ wk,
    const float* __restrict__ wv, unsigned short* __restrict__ wt)
{
    int idx = blockIdx.x * 256 + threadIdx.x;   // 786432 total
    int n   = idx & 127;
    int k   = (idx >> 7) & 2047;
    int sel = idx >> 18;                        // 0,1,2
    const float* w = (sel == 0) ? wq : (sel == 1) ? wk : wv;
    wt[(size_t)(sel * 128 + n) * 2048 + k] = f2bf(w[k * 128 + n]);
}

// ---------------------------------------------------------------------------
// Kernel 2: QKV GEMM (x fp32 -> bf16 staged) + RoPE epilogue.
//   ntile 0 -> Q (RoPE, linear layout)
//   ntile 1 -> K (RoPE, XOR-swizzled within each 128B half-row: T2 swizzle)
//   ntile 2 -> V transposed [128][2048], XOR-swizzled within 128B (64-t) chunks
// ---------------------------------------------------------------------------
__global__ __launch_bounds__(256) void qkv_gemm(
    const float* __restrict__ x, const unsigned short* __restrict__ wt,
    const float* __restrict__ rc, const float* __restrict__ rs,
    unsigned short* __restrict__ Qb, unsigned short* __restrict__ Kb,
    unsigned short* __restrict__ VT)
{
    __shared__ __align__(16) unsigned short As[2][128 * 32];
    __shared__ __align__(16) unsigned short Bs[2][128 * 32];

    const int bid   = blockIdx.x;           // 384
    const int slot  = bid & 7;
    const int idx   = bid >> 3;             // 0..47
    const int mtile = slot + 8 * (idx / 3);
    const int ntile = idx % 3;

    const int tid  = threadIdx.x;
    const int lane = tid & 63;
    const int wid  = tid >> 6;
    const int wm   = wid >> 1, wn = wid & 1;
    const int grp  = lane >> 4, cl = lane & 15;

    const int arow0 = tid >> 2;
    const int ak8   = tid & 3;

    const float*          xbase = x  + (size_t)(mtile * 128) * 2048;
    const unsigned short* wbase = wt + (size_t)(ntile * 128) * 2048;

    float4 afl[2][2];
    u16x8  bwl[2];

    auto gload = [&](int ks) {
        int k0 = ks * 32 + ak8 * 8;
        #pragma unroll
        for (int i = 0; i < 2; ++i) {
            int row = arow0 + i * 64;
            const float* p = xbase + (size_t)row * 2048 + k0;
            afl[i][0] = *reinterpret_cast<const float4*>(p);
            afl[i][1] = *reinterpret_cast<const float4*>(p + 4);
            bwl[i]    = *reinterpret_cast<const u16x8*>(wbase + (size_t)row * 2048 + k0);
        }
    };
    auto swrite = [&](int buf) {
        #pragma unroll
        for (int i = 0; i < 2; ++i) {
            int row = arow0 + i * 64;
            u16x8 u;
            u[0] = f2bf(afl[i][0].x); u[1] = f2bf(afl[i][0].y);
            u[2] = f2bf(afl[i][0].z); u[3] = f2bf(afl[i][0].w);
            u[4] = f2bf(afl[i][1].x); u[5] = f2bf(afl[i][1].y);
            u[6] = f2bf(afl[i][1].z); u[7] = f2bf(afl[i][1].w);
            *reinterpret_cast<u16x8*>(&As[buf][row * 32 + ak8 * 8]) = u;
            *reinterpret_cast<u16x8*>(&Bs[buf][row * 32 + ak8 * 8]) = bwl[i];
        }
    };

    const f32x4 fz = {0.f, 0.f, 0.f, 0.f};
    f32x4 acc[4][4];
    #pragma unroll
    for (int mf = 0; mf < 4; ++mf)
        #pragma unroll
        for (int nf = 0; nf < 4; ++nf) acc[mf][nf] = fz;

    gload(0);
    swrite(0);
    __syncthreads();

    for (int ks = 0; ks < 64; ++ks) {
        int cur = ks & 1;
        if (ks < 63) gload(ks + 1);

        bf16x8 a[4], b[4];
        #pragma unroll
        for (int mf = 0; mf < 4; ++mf)
            a[mf] = *reinterpret_cast<const bf16x8*>(
                &As[cur][(wm * 64 + mf * 16 + cl) * 32 + grp * 8]);
        #pragma unroll
        for (int nf = 0; nf < 4; ++nf)
            b[nf] = *reinterpret_cast<const bf16x8*>(
                &Bs[cur][(wn * 64 + nf * 16 + cl) * 32 + grp * 8]);
        #pragma unroll
        for (int mf = 0; mf < 4; ++mf)
            #pragma unroll
            for (int nf = 0; nf < 4; ++nf)
                acc[mf][nf] = __builtin_amdgcn_mfma_f32_16x16x32_bf16(
                    a[mf], b[nf], acc[mf][nf], 0, 0, 0);

        if (ks < 63) swrite(cur ^ 1);
        __syncthreads();
    }

    // Epilogue. C-layout: col = lane&15, row = (lane>>4)*4 + r
    if (ntile == 0) {
        #pragma unroll
        for (int mf = 0; mf < 4; ++mf) {
            int mrow = mtile * 128 + wm * 64 + mf * 16 + grp * 4;
            #pragma unroll
            for (int nf = 0; nf < 4; ++nf) {
                int h = wn * 64 + nf * 16 + cl;
                #pragma unroll
                for (int r = 0; r < 4; ++r) {
                    int   m   = mrow + r;
                    int   t   = m & 2047;
                    float val = acc[mf][nf][r];
                    float pr  = __shfl_xor(val, 1, 64);
                    float cs  = rc[t * 128 + h];
                    float sn  = rs[t * 128 + h];
                    float res = (h & 1) ? fmaf(val, cs, pr * sn)
                                        : fmaf(val, cs, -pr * sn);
                    Qb[(size_t)m * 128 + h] = f2bf(res);
                }
            }
        }
    } else if (ntile == 1) {
        #pragma unroll
        for (int mf = 0; mf < 4; ++mf) {
            int mrow = mtile * 128 + wm * 64 + mf * 16 + grp * 4;
            #pragma unroll
            for (int nf = 0; nf < 4; ++nf) {
                int h = wn * 64 + nf * 16 + cl;
                #pragma unroll
                for (int r = 0; r < 4; ++r) {
                    int   m   = mrow + r;
                    int   t   = m & 2047;
                    float val = acc[mf][nf][r];
                    float pr  = __shfl_xor(val, 1, 64);
                    float cs  = rc[t * 128 + h];
                    float sn  = rs[t * 128 + h];
                    float res = (h & 1) ? fmaf(val, cs, pr * sn)
                                        : fmaf(val, cs, -pr * sn);
                    int bo = h * 2;
                    int bs = (bo & 128) | ((bo & 127) ^ ((m & 7) << 4));
                    Kb[(size_t)m * 128 + (bs >> 1)] = f2bf(res);
                }
            }
        }
    } else {
        #pragma unroll
        for (int mf = 0; mf < 4; ++mf) {
            int mrow = mtile * 128 + wm * 64 + mf * 16 + grp * 4;
            int bb   = mrow >> 11;
            int t0   = mrow & 2047;
            #pragma unroll
            for (int nf = 0; nf < 4; ++nf) {
                int h = wn * 64 + nf * 16 + cl;
                u16x4 pk;
                #pragma unroll
                for (int r = 0; r < 4; ++r) pk[r] = f2bf(acc[mf][nf][r]);
                int bo = (t0 * 2) & 127;
                int bs = ((t0 * 2) & ~127) | (bo ^ ((h & 7) << 4));
                *reinterpret_cast<u16x4*>(
                    &VT[(size_t)(bb * 128 + h) * 2048 + (bs >> 1)]) = pk;
            }
        }
    }
}

// ---------------------------------------------------------------------------
// Kernel 3: causal flash attention v2.
//   4 waves/block, Q-tile 64 (16 rows/wave), KV-tile 64 staged in LDS
//   (double-buffered global_load_lds, pre-swizzled global K/V), KV-split into
//   `nchunk` chunks with unnormalized partials + merge. Heavy tiles first.
// ---------------------------------------------------------------------------
__global__ __launch_bounds__(256, 2) void flash_attn(
    const unsigned short* __restrict__ Qb, const unsigned short* __restrict__ Kb,
    const unsigned short* __restrict__ VT, float* __restrict__ Op,
    float2* __restrict__ ML, float* __restrict__ out, int nchunk)
{
    __shared__ __align__(16) unsigned short Ks[2][64 * 128];
    __shared__ __align__(16) unsigned short Vs[2][128 * 64];
    __shared__ __align__(16) unsigned short Ps[4][16 * 72];

    const int g      = blockIdx.x;
    const int per_mt = 8 * nchunk;
    const int mtd    = g / per_mt;
    const int mt     = 31 - mtd;
    const int rem    = g - mtd * per_mt;
    const int c      = rem >> 3;
    const int b      = rem & 7;

    const int tid  = threadIdx.x;
    const int lane = tid & 63;
    const int w    = tid >> 6;
    const int grp  = lane >> 4, cl = lane & 15;

    const int NT   = mt + 1;
    const int T0   = (NT + 1) >> 1;
    const int tbeg = (nchunk == 2 && c == 1) ? T0 : 0;
    const int tend = (nchunk == 2 && c == 0) ? T0 : NT;

    const int   q0    = mt * 64 + w * 16;
    const float scale = 0.08838834764831845f;   // 1/sqrt(128)

    bf16x8 aq[4];
    {
        const unsigned short* qp = Qb + (size_t)(b * 2048 + q0 + cl) * 128 + grp * 8;
        #pragma unroll
        for (int kc = 0; kc < 4; ++kc)
            aq[kc] = *reinterpret_cast<const bf16x8*>(qp + kc * 32);
    }

    const f32x4 fz = {0.f, 0.f, 0.f, 0.f};
    f32x4 o[8];
    #pragma unroll
    for (int nf = 0; nf < 8; ++nf) o[nf] = fz;
    float mrun[4], lrun[4];
    #pragma unroll
    for (int r = 0; r < 4; ++r) { mrun[r] = -INFINITY; lrun[r] = 0.f; }

    const char* kgb = (const char*)(Kb + (size_t)b * 2048 * 128);
    const char* vgb = (const char*)(VT + (size_t)b * 128 * 2048);

    auto stage = [&](int d, int t) {
        const char* ks = kgb + (size_t)t * 64 * 256;
        char* kd = (char*)&Ks[d][0];
        #pragma unroll
        for (int i = 0; i < 4; ++i) {
            int off = w * 4096 + i * 1024 + lane * 16;
            cp16(kd + off, ks + off);
        }
        const char* vsb = vgb + (size_t)t * 128;
        char* vd = (char*)&Vs[d][0];
        #pragma unroll
        for (int i = 0; i < 4; ++i) {
            int off = w * 4096 + i * 1024 + lane * 16;
            cp16(vd + off, vsb + (size_t)(off >> 7) * 4096 + (off & 127));
        }
    };

    if (tbeg < tend) stage(0, tbeg);
    __syncthreads();

    int cur = 0;
    for (int t = tbeg; t < tend; ++t) {
        if (t + 1 < tend) stage(cur ^ 1, t + 1);

        const char* kb   = (const char*)&Ks[cur][0];
        const char* vb   = (const char*)&Vs[cur][0];
        const bool  diag = (t == mt);
        const int   jmax = diag ? (w + 1) : 4;

        float p[4][4];
        float mx[4];
        #pragma unroll
        for (int r = 0; r < 4; ++r) mx[r] = -INFINITY;

        #pragma unroll
        for (int j = 0; j < 4; ++j) {
            #pragma unroll
            for (int r = 0; r < 4; ++r) p[j][r] = 0.f;
            if (j < jmax) {
                int   row = j * 16 + cl;
                f32x4 s   = fz;
                #pragma unroll
                for (int kc = 0; kc < 4; ++kc) {
                    int bo = kc * 64 + grp * 16;
                    int bs = (bo & 128) | ((bo & 127) ^ ((row & 7) << 4));
                    bf16x8 kf = *reinterpret_cast<const bf16x8*>(kb + row * 256 + bs);
                    s = __builtin_amdgcn_mfma_f32_16x16x32_bf16(aq[kc], kf, s, 0, 0, 0);
                }
                #pragma unroll
                for (int r = 0; r < 4; ++r) {
                    float a = s[r] * scale;
                    if (diag && j == w && cl > grp * 4 + r) a = -INFINITY;
                    p[j][r] = a;
                    mx[r]   = fmaxf(mx[r], a);
                }
            }
        }
        #pragma unroll
        for (int d = 1; d < 16; d <<= 1)
            #pragma unroll
            for (int r = 0; r < 4; ++r)
                mx[r] = fmaxf(mx[r], __shfl_xor(mx[r], d, 64));

        float alpha[4], psum[4];
        #pragma unroll
        for (int r = 0; r < 4; ++r) {
            float mn = fmaxf(mrun[r], mx[r]);
            alpha[r] = __expf(mrun[r] - mn);
            mrun[r]  = mn;
            psum[r]  = 0.f;
        }
        #pragma unroll
        for (int j = 0; j < 4; ++j)
            if (j < jmax)
                #pragma unroll
                for (int r = 0; r < 4; ++r) {
                    p[j][r] = __expf(p[j][r] - mrun[r]);
                    psum[r] += p[j][r];
                }
        #pragma unroll
        for (int d = 1; d < 16; d <<= 1)
            #pragma unroll
            for (int r = 0; r < 4; ++r)
                psum[r] += __shfl_xor(psum[r], d, 64);
        #pragma unroll
        for (int r = 0; r < 4; ++r)
            lrun[r] = lrun[r] * alpha[r] + psum[r];
        #pragma unroll
        for (int nf = 0; nf < 8; ++nf)
            #pragma unroll
            for (int r = 0; r < 4; ++r) o[nf][r] *= alpha[r];

        // P -> LDS (per-wave private, XOR-swizzled rows, stride 72 elements)
        char* pwb = (char*)&Ps[w][0];
        #pragma unroll
        for (int j = 0; j < 4; ++j)
            #pragma unroll
            for (int r = 0; r < 4; ++r) {
                int prow = grp * 4 + r;
                int bytec = ((j * 16 + cl) * 2) ^ ((prow & 7) << 4);
                *reinterpret_cast<unsigned short*>(pwb + prow * 144 + bytec) =
                    f2bf(p[j][r]);
            }

        const char* pb = (const char*)&Ps[w][0];
        #pragma unroll
        for (int half = 0; half < 2; ++half) {
            int pbo = half * 64 + grp * 16;
            bf16x8 pa = *reinterpret_cast<const bf16x8*>(
                pb + cl * 144 + (pbo ^ ((cl & 7) << 4)));
            #pragma unroll
            for (int nf = 0; nf < 8; ++nf) {
                int h  = nf * 16 + cl;
                int bs = (half * 64 + grp * 16) ^ ((h & 7) << 4);
                bf16x8 vf = *reinterpret_cast<const bf16x8*>(vb + h * 128 + bs);
                o[nf] = __builtin_amdgcn_mfma_f32_16x16x32_bf16(pa, vf, o[nf], 0, 0, 0);
            }
        }
        __syncthreads();
        cur ^= 1;
    }

    if (nchunk == 2) {
        #pragma unroll
        for (int nf = 0; nf < 8; ++nf)
            #pragma unroll
            for (int r = 0; r < 4; ++r) {
                size_t rowg = (size_t)c * 16384 + b * 2048 + q0 + grp * 4 + r;
                Op[rowg * 128 + nf * 16 + cl] = o[nf][r];
            }
        if (cl == 0)
            #pragma unroll
            for (int r = 0; r < 4; ++r)
                ML[(size_t)c * 16384 + b * 2048 + q0 + grp * 4 + r] =
                    make_float2(mrun[r], lrun[r]);
    } else {
        float inv[4];
        #pragma unroll
        for (int r = 0; r < 4; ++r) inv[r] = 1.0f / lrun[r];
        #pragma unroll
        for (int nf = 0; nf < 8; ++nf)
            #pragma unroll
            for (int r = 0; r < 4; ++r)
                out[(size_t)(b * 2048 + q0 + grp * 4 + r) * 128 + nf * 16 + cl] =
                    o[nf][r] * inv[r];
    }
}

// ---------------------------------------------------------------------------
// Kernel 4: merge the 2 KV-chunk partials: out = sum_c o_c e^{m_c-m} / l
// ---------------------------------------------------------------------------
__global__ __launch_bounds__(256) void merge2(
    const float* __restrict__ Op, const float2* __restrict__ ML,
    float* __restrict__ out)
{
    int idx = blockIdx.x * 256 + threadIdx.x;   // 16384*32
    int row = idx >> 5, hq = idx & 31;
    float2 ml0 = ML[row];
    float2 ml1 = ML[16384 + row];
    float  m  = fmaxf(ml0.x, ml1.x);
    float  e0 = __expf(ml0.x - m);
    float  e1 = __expf(ml1.x - m);
    float  inv = 1.0f / (ml0.y * e0 + ml1.y * e1);
    f32x4 o0 = *reinterpret_cast<const f32x4*>(Op + (size_t)row * 128 + hq * 4);
    f32x4 o1 = *reinterpret_cast<const f32x4*>(Op + ((size_t)16384 + row) * 128 + hq * 4);
    f32x4 res;
    #pragma unroll
    for (int i = 0; i < 4; ++i) res[i] = (o0[i] * e0 + o1[i] * e1) * inv;
    *reinterpret_cast<f32x4*>(out + (size_t)row * 128 + hq * 4) = res;
}

// ---------------------------------------------------------------------------
extern "C" void kernel_launch(void* const* d_in, const int* in_sizes, int n_in,
                              void* d_out, int out_size, void* d_ws, size_t ws_size,
                              hipStream_t stream)
{
    const float* x  = (const float*)d_in[0];
    const float* wq = (const float*)d_in[1];
    const float* wk = (const float*)d_in[2];
    const float* wv = (const float*)d_in[3];
    const float* rc = (const float*)d_in[4];
    const float* rs = (const float*)d_in[5];
    float* out = (float*)d_out;

    char* ws = (char*)d_ws;
    unsigned short* wt = (unsigned short*)(ws);                  // 1.5 MB
    unsigned short* Qb = (unsigned short*)(ws + (2u  << 20));    // 4 MB
    unsigned short* Kb = (unsigned short*)(ws + (6u  << 20));    // 4 MB
    unsigned short* VT = (unsigned short*)(ws + (10u << 20));    // 4 MB
    float*          Op = (float*)        (ws + (14u << 20));     // 16 MB (2 chunks)
    float2*         ML = (float2*)       (ws + (30u << 20));     // 256 KB

    const int nchunk = (ws_size >= ((size_t)31 << 20)) ? 2 : 1;

    pack_w    <<<3072, 256, 0, stream>>>(wq, wk, wv, wt);
    qkv_gemm  <<<384,  256, 0, stream>>>(x, wt, rc, rs, Qb, Kb, VT);
    flash_attn<<<32 * 8 * nchunk, 256, 0, stream>>>(Qb, Kb, VT, Op, ML, out, nchunk);
    if (nchunk == 2)
        merge2<<<2048, 256, 0, stream>>>(Op, ML, out);
}